// Round 1
// baseline (416.546 us; speedup 1.0000x reference)
//
#include <hip/hip_runtime.h>
#include <math.h>

// Problem constants (fixed by the reference).
#define NN 8192
#define DD 64
#define SS 4096
#define BETA0 0.1
#define BETA1 0.1

// ws layout: double acc[4] (lsh, ltr, smooth, pad), then float diag[NN].

__global__ void init_acc_kernel(double* acc) {
    if (threadIdx.x < 4) acc[threadIdx.x] = 0.0;
}

// One wave (64 lanes) per row: diag[l] = theta_l . E_l
__global__ void diag_kernel(const float* __restrict__ E,
                            const float* __restrict__ theta,
                            float* __restrict__ diag) {
    int gid  = blockIdx.x * blockDim.x + threadIdx.x;
    int row  = gid >> 6;
    int lane = gid & 63;
    if (row < NN) {
        float v = theta[(size_t)row * DD + lane] * E[(size_t)row * DD + lane];
        #pragma unroll
        for (int o = 32; o; o >>= 1) v += __shfl_down(v, o);
        if (lane == 0) diag[row] = v;
    }
}

// sum((emb_t - emb_prev)^2) over N*D elements, float4 vectorized.
__global__ void smooth_kernel(const float4* __restrict__ a,
                              const float4* __restrict__ b,
                              double* __restrict__ acc) {
    const int total = NN * DD / 4;
    int idx = blockIdx.x * blockDim.x + threadIdx.x;
    float sum = 0.f;
    for (int t = idx; t < total; t += gridDim.x * blockDim.x) {
        float4 x = a[t], y = b[t];
        float d0 = x.x - y.x, d1 = x.y - y.y, d2 = x.z - y.z, d3 = x.w - y.w;
        sum += d0 * d0 + d1 * d1 + d2 * d2 + d3 * d3;
    }
    #pragma unroll
    for (int o = 32; o; o >>= 1) sum += __shfl_down(sum, o);
    __shared__ float wsum[4];
    int lane = threadIdx.x & 63, wv = threadIdx.x >> 6;
    if (lane == 0) wsum[wv] = sum;
    __syncthreads();
    if (threadIdx.x == 0)
        atomicAdd(&acc[2], (double)(wsum[0] + wsum[1] + wsum[2] + wsum[3]));
}

// One block (256 threads) per sample.
__global__ void __launch_bounds__(256) sample_kernel(
        const float* __restrict__ E, const float* __restrict__ theta,
        const float* __restrict__ adj, const float* __restrict__ diag,
        const int* __restrict__ j_idx, const int* __restrict__ k_idx,
        const int* __restrict__ nj_idx, const int* __restrict__ i_idx,
        const int* __restrict__ cond, double* __restrict__ acc) {
    int s   = blockIdx.x;
    int tid = threadIdx.x;
    int j = j_idx[s], k = k_idx[s], nj = nj_idx[s], i = i_idx[s], c = cond[s];

    __shared__ float ui_sh[DD], uj_sh[DD];
    __shared__ float sc[4];     // pos, neg, tik, tjk
    __shared__ float wprod[4];

    if (tid < DD) {
        float ui_ = E[(size_t)i * DD + tid];
        float uj_ = E[(size_t)j * DD + tid];
        ui_sh[tid] = ui_;
        uj_sh[tid] = uj_;
        float uk_ = E[(size_t)k * DD + tid];
        float un_ = E[(size_t)nj * DD + tid];
        float thk = theta[(size_t)k * DD + tid];
        float dp = uj_ - uk_, dn = un_ - uk_;
        float pos = dp * dp, neg = dn * dn;
        float tik = thk * ui_, tjk = thk * uj_;
        #pragma unroll
        for (int o = 32; o; o >>= 1) {
            pos += __shfl_down(pos, o);
            neg += __shfl_down(neg, o);
            tik += __shfl_down(tik, o);
            tjk += __shfl_down(tjk, o);
        }
        if (tid == 0) { sc[0] = pos; sc[1] = neg; sc[2] = tik; sc[3] = tjk; }
    }
    __syncthreads();

    float prodAll = 1.0f;
    if (c == 1) {   // block-uniform branch: only cond==1 needs C1
        float prod = 1.0f;
        const float4* ri = (const float4*)(adj + (size_t)i * NN);
        const float4* rj = (const float4*)(adj + (size_t)j * NN);
        for (int b = tid; b < NN / 4; b += 256) {
            float4 a4 = ri[b];
            float4 b4 = rj[b];
            float ai[4] = {a4.x, a4.y, a4.z, a4.w};
            float aj[4] = {b4.x, b4.y, b4.z, b4.w};
            #pragma unroll
            for (int q = 0; q < 4; q++) {
                if (ai[q] > 0.f && aj[q] > 0.f) {
                    int l = b * 4 + q;
                    const float* th = theta + (size_t)l * DD;
                    float til = 0.f, tjl = 0.f;
                    for (int d = 0; d < DD; d++) {
                        float t = th[d];
                        til = fmaf(t, ui_sh[d], til);
                        tjl = fmaf(t, uj_sh[d], tjl);
                    }
                    float dg = diag[l];
                    float dl = ai[q] * (dg - til) + aj[q] * (dg - tjl);
                    float P = (dl < -100.f) ? 0.f : 1.f / (1.f + expf(-dl));
                    prod *= (1.f - P);
                }
            }
        }
        #pragma unroll
        for (int o = 32; o; o >>= 1) prod *= __shfl_down(prod, o);
        int lane = tid & 63, wv = tid >> 6;
        if (lane == 0) wprod[wv] = prod;
        __syncthreads();
        if (tid == 0) prodAll = wprod[0] * wprod[1] * wprod[2] * wprod[3];
    }

    if (tid == 0) {
        float pos = sc[0], neg = sc[1], tik = sc[2], tjk = sc[3];
        float lsh = fmaxf(pos - neg + 1.0f, 0.f);

        float aik = adj[(size_t)i * NN + k];
        float ajk = adj[(size_t)j * NN + k];
        float dgk = diag[k];
        float dot_k = aik * (dgk - tik) + ajk * (dgk - tjk);

        float x = -dot_k;  // softplus(-dot_k), numerically stable
        float logp = fmaxf(x, 0.f) + log1pf(expf(-fabsf(x)));

        float ltr;
        if (c == -1) {
            ltr = 0.f;
        } else if (c == 0) {
            ltr = logp + dot_k;
        } else {
            float C1 = 1.f - prodAll;
            float C0 = (dot_k < -100.f) ? 0.f : 1.f / (1.f + expf(-dot_k));
            ltr = logp + (1.f - C0 / (C1 + 1e-6f));
        }
        atomicAdd(&acc[0], (double)lsh);
        atomicAdd(&acc[1], (double)ltr);
    }
}

__global__ void final_kernel(const double* __restrict__ acc,
                             float* __restrict__ out) {
    if (blockIdx.x == 0 && threadIdx.x == 0) {
        double loss = acc[0] + BETA0 * acc[1] + BETA1 * (double)SS * acc[2];
        out[0] = (float)loss;
    }
}

extern "C" void kernel_launch(void* const* d_in, const int* in_sizes, int n_in,
                              void* d_out, int out_size, void* d_ws, size_t ws_size,
                              hipStream_t stream) {
    const float* emb_t    = (const float*)d_in[0];
    const float* emb_prev = (const float*)d_in[1];
    const float* theta    = (const float*)d_in[2];
    const float* adj      = (const float*)d_in[3];
    const int*   j_idx    = (const int*)d_in[4];
    const int*   k_idx    = (const int*)d_in[5];
    const int*   nj_idx   = (const int*)d_in[6];
    const int*   i_idx    = (const int*)d_in[7];
    const int*   cond     = (const int*)d_in[8];
    float* out = (float*)d_out;

    double* acc  = (double*)d_ws;
    float*  diag = (float*)(acc + 4);

    init_acc_kernel<<<1, 64, 0, stream>>>(acc);
    diag_kernel<<<(NN * 64) / 256, 256, 0, stream>>>(emb_t, theta, diag);
    smooth_kernel<<<256, 256, 0, stream>>>((const float4*)emb_t,
                                           (const float4*)emb_prev, acc);
    sample_kernel<<<SS, 256, 0, stream>>>(emb_t, theta, adj, diag,
                                          j_idx, k_idx, nj_idx, i_idx, cond, acc);
    final_kernel<<<1, 64, 0, stream>>>(acc, out);
}

// Round 2
// 341.322 us; speedup vs baseline: 1.2204x; 1.2204x over previous
//
#include <hip/hip_runtime.h>
#include <math.h>

#define NN 8192
#define DD 64
#define SS 4096

// Butterfly reduce: result replicated on all 64 lanes.
__device__ __forceinline__ float wred(float v) {
    #pragma unroll
    for (int o = 1; o < 64; o <<= 1) v += __shfl_xor(v, o);
    return v;
}

// One wave (64 lanes) per sample. 4 waves per block. No atomics, no barriers.
__global__ void __launch_bounds__(256) fused_sample_kernel(
        const float* __restrict__ E, const float* __restrict__ Eprev,
        const float* __restrict__ theta, const float* __restrict__ adj,
        const int* __restrict__ j_idx, const int* __restrict__ k_idx,
        const int* __restrict__ nj_idx, const int* __restrict__ i_idx,
        const int* __restrict__ cond, float4* __restrict__ part) {
    int wave = threadIdx.x >> 6;
    int lane = threadIdx.x & 63;
    int s = blockIdx.x * 4 + wave;

    int j = j_idx[s], k = k_idx[s], nj = nj_idx[s], i = i_idx[s], c = cond[s];

    // ---- coalesced row gathers: lane d holds element d ----
    float ui  = E[(size_t)i  * DD + lane];
    float uj  = E[(size_t)j  * DD + lane];
    float uk  = E[(size_t)k  * DD + lane];
    float un  = E[(size_t)nj * DD + lane];
    float thk = theta[(size_t)k * DD + lane];

    float dp = uj - uk, dn = un - uk;
    float pos = wred(dp * dp);
    float neg = wred(dn * dn);
    float tik = wred(thk * ui);
    float tjk = wred(thk * uj);
    float dgk = wred(thk * uk);   // diag[k] = theta_k . u_k

    // ---- L_smooth slice: this wave covers float2 chunk [s*64, s*64+64) ----
    float sm;
    {
        const float2* a2 = (const float2*)E;
        const float2* b2 = (const float2*)Eprev;
        float2 x = a2[(size_t)s * 64 + lane];
        float2 y = b2[(size_t)s * 64 + lane];
        float dx = x.x - y.x, dy = x.y - y.y;
        sm = wred(dx * dx + dy * dy);
    }

    // ---- C1 product: only condition==1 needs the common-neighbor scan ----
    float prod = 1.0f;   // replicated across lanes
    if (c == 1) {        // wave-uniform branch
        const float4* ri = (const float4*)(adj + (size_t)i * NN);
        const float4* rj = (const float4*)(adj + (size_t)j * NN);
        #pragma unroll 2
        for (int it = 0; it < NN / 4 / 64; ++it) {   // 32 iterations
            float4 a4 = ri[it * 64 + lane];
            float4 b4 = rj[it * 64 + lane];
            float av[4] = {a4.x, a4.y, a4.z, a4.w};
            float bv[4] = {b4.x, b4.y, b4.z, b4.w};
            #pragma unroll
            for (int q = 0; q < 4; ++q) {
                unsigned long long m = __ballot(av[q] > 0.f && bv[q] > 0.f);
                while (m) {   // rare: ~0.13 hits per sample on average
                    int src = __ffsll((long long)m) - 1;
                    m &= m - 1;
                    float ai = __shfl(av[q], src);
                    float aj = __shfl(bv[q], src);
                    int l = (it * 64 + src) * 4 + q;
                    float th = theta[(size_t)l * DD + lane];
                    float ul = E[(size_t)l * DD + lane];
                    float r1 = wred(th * (ul - ui));   // diag[l] - theta_l.u_i
                    float r2 = wred(th * (ul - uj));   // diag[l] - theta_l.u_j
                    float dl = ai * r1 + aj * r2;
                    float P = (dl < -100.f) ? 0.f : 1.f / (1.f + __expf(-dl));
                    prod *= (1.f - P);
                }
            }
        }
    }

    if (lane == 0) {
        float lsh = fmaxf(pos - neg + 1.0f, 0.f);

        float aik = adj[(size_t)i * NN + k];
        float ajk = adj[(size_t)j * NN + k];
        float dot_k = aik * (dgk - tik) + ajk * (dgk - tjk);

        float x = -dot_k;   // softplus(-dot_k)
        float logp = fmaxf(x, 0.f) + log1pf(expf(-fabsf(x)));

        float ltr;
        if (c == -1) {
            ltr = 0.f;
        } else if (c == 0) {
            ltr = logp + dot_k;
        } else {
            float C1 = 1.f - prod;
            float C0 = (dot_k < -100.f) ? 0.f : 1.f / (1.f + expf(-dot_k));
            ltr = logp + (1.f - C0 / (C1 + 1e-6f));
        }
        part[s] = make_float4(lsh, ltr, sm, 0.f);
    }
}

// Single block: reduce 4096 float4 partials in double, emit the scalar loss.
__global__ void __launch_bounds__(256) final_reduce_kernel(
        const float4* __restrict__ part, float* __restrict__ out) {
    double lsh = 0.0, ltr = 0.0, sm = 0.0;
    for (int t = threadIdx.x; t < SS; t += 256) {
        float4 p = part[t];
        lsh += (double)p.x;
        ltr += (double)p.y;
        sm  += (double)p.z;
    }
    #pragma unroll
    for (int o = 32; o; o >>= 1) {
        lsh += __shfl_down(lsh, o);
        ltr += __shfl_down(ltr, o);
        sm  += __shfl_down(sm, o);
    }
    __shared__ double sh[3][4];
    int lane = threadIdx.x & 63, wv = threadIdx.x >> 6;
    if (lane == 0) { sh[0][wv] = lsh; sh[1][wv] = ltr; sh[2][wv] = sm; }
    __syncthreads();
    if (threadIdx.x == 0) {
        double L = (sh[0][0] + sh[0][1] + sh[0][2] + sh[0][3])
                 + 0.1 * (sh[1][0] + sh[1][1] + sh[1][2] + sh[1][3])
                 + 0.1 * (double)SS * (sh[2][0] + sh[2][1] + sh[2][2] + sh[2][3]);
        out[0] = (float)L;
    }
}

extern "C" void kernel_launch(void* const* d_in, const int* in_sizes, int n_in,
                              void* d_out, int out_size, void* d_ws, size_t ws_size,
                              hipStream_t stream) {
    const float* emb_t    = (const float*)d_in[0];
    const float* emb_prev = (const float*)d_in[1];
    const float* theta    = (const float*)d_in[2];
    const float* adj      = (const float*)d_in[3];
    const int*   j_idx    = (const int*)d_in[4];
    const int*   k_idx    = (const int*)d_in[5];
    const int*   nj_idx   = (const int*)d_in[6];
    const int*   i_idx    = (const int*)d_in[7];
    const int*   cond     = (const int*)d_in[8];
    float* out = (float*)d_out;

    float4* part = (float4*)d_ws;   // 4096 * 16 B = 64 KiB

    fused_sample_kernel<<<SS / 4, 256, 0, stream>>>(
        emb_t, emb_prev, theta, adj, j_idx, k_idx, nj_idx, i_idx, cond, part);
    final_reduce_kernel<<<1, 256, 0, stream>>>(part, out);
}